// Round 8
// baseline (157.281 us; speedup 1.0000x reference)
//
#include <hip/hip_runtime.h>
#include <math.h>

#define NPOS  16384
#define LBAG  30
#define NFEAT 40960
#define HDIM  512          // per side
#define MT    16           // positions per block

typedef short bf16x8 __attribute__((ext_vector_type(8)));
typedef float f32x4  __attribute__((ext_vector_type(4)));
typedef unsigned int u32x4 __attribute__((ext_vector_type(4)));

__device__ __forceinline__ unsigned int f2bf(float f) {
    unsigned int u = __float_as_uint(f);
    return (u + 0x7fffu + ((u >> 16) & 1u)) >> 16;
}
__device__ __forceinline__ float clip01(float v) { return fminf(fmaxf(v, 0.f), 1.f); }

// ---------------------------------------------------------------------------
// Prep 1: emb fp32 -> bf16 (pairs packed in uint). 84MB read + 42MB write.
// ---------------------------------------------------------------------------
__global__ __launch_bounds__(256) void cvt_emb(const float* __restrict__ src,
                                               unsigned int* __restrict__ dst) {
    const int nchunk = NFEAT * HDIM / 8;
    int c = blockIdx.x * 256 + threadIdx.x;
    const int stride = gridDim.x * 256;
    for (; c < nchunk; c += stride) {
        float4 f0 = ((const float4*)src)[(size_t)c * 2];
        float4 f1 = ((const float4*)src)[(size_t)c * 2 + 1];
        uint4 o;
        o.x = f2bf(f0.x) | (f2bf(f0.y) << 16);
        o.y = f2bf(f0.z) | (f2bf(f0.w) << 16);
        o.z = f2bf(f1.x) | (f2bf(f1.y) << 16);
        o.w = f2bf(f1.z) | (f2bf(f1.w) << 16);
        ((uint4*)dst)[c] = o;
    }
}

// ---------------------------------------------------------------------------
// Prep 2: W1 [128][1024] fp32 -> bf16 in MFMA B-fragment order.
//   B[k][j] = W1[j][k], j = nf*16 + (lane&15), k = ks*32 + (lane>>4)*8 + b
// ---------------------------------------------------------------------------
__global__ __launch_bounds__(256) void prep_w1(const float* __restrict__ W1,
                                               unsigned int* __restrict__ dst) {
    int c = blockIdx.x * 256 + threadIdx.x;
    if (c >= 8 * 32 * 64) return;
    int l  = c & 63;
    int ks = (c >> 6) & 31;
    int nf = c >> 11;
    int o  = nf * 16 + (l & 15);
    int kb = ks * 32 + (l >> 4) * 8;
    float4 f0 = *(const float4*)(W1 + (size_t)o * 1024 + kb);
    float4 f1 = *(const float4*)(W1 + (size_t)o * 1024 + kb + 4);
    uint4 v;
    v.x = f2bf(f0.x) | (f2bf(f0.y) << 16);
    v.y = f2bf(f0.z) | (f2bf(f0.w) << 16);
    v.z = f2bf(f1.x) | (f2bf(f1.y) << 16);
    v.w = f2bf(f1.z) | (f2bf(f1.w) << 16);
    ((uint4*)dst)[c] = v;
}

// ---------------------------------------------------------------------------
// Fused kernel, round 8: FORCED 8-deep gather ILP via inline asm.
// r7 evidence: VGPR=56 proves the compiler kept <=4 loads in flight (the fp32
// acc chain is non-reassociable, so it interleaved load/consume to save regs);
// the r7 "ILP experiment" never ran. Here 8 global_load_dwordx4 are issued as
// volatile asm (program order guaranteed), then s_waitcnt vmcnt(0) +
// sched_barrier(0) (rule #18), then consume. Next ids prefetched under the
// vm wait. ~90-120 VGPR expected.
//
// LDS map (36608 B): [0,32768) x tile (phase1) / h1|w2|h2 (phase2);
//                    [32768,36608) sidx[32 bags][30].
// Swizzle: byte = row*2048 + (col ^ ((row&7)<<4)) on write and A-frag read.
// MFMA 16x16x32_bf16: A row=lane&15, k=(lane>>4)*8+b; C/D col=lane&15,
// row=(lane>>4)*4+reg [m89]. Wave w covers nf = 2w, 2w+1.
// ---------------------------------------------------------------------------
__global__ __launch_bounds__(256, 4) void nnue_fused(
    const int* __restrict__ stm_idx, const int* __restrict__ nstm_idx,
    const unsigned int* __restrict__ embbf,     // [NFEAT][512] bf16
    const unsigned int* __restrict__ w1f,       // frag-ordered bf16
    const float* __restrict__ b1,
    const float* __restrict__ W2, const float* __restrict__ b2,
    const float* __restrict__ W3, const float* __restrict__ b3,
    float* __restrict__ out)
{
    __shared__ __align__(16) char smem[36608];
    char* xb   = smem;
    int*  sidx = (int*)(smem + 32768);
    float* h1  = (float*)smem;                  // [16][132]
    float* w2  = (float*)smem + 16 * 132;       // [32][132]
    float* h2  = (float*)smem + 48 * 132;       // [16][33]

    const int t    = threadIdx.x;               // 0..255
    const int pblk = blockIdx.x * MT;
    const int w    = t >> 6;                    // wave 0..3
    const int lane = t & 63;

    // ---- stage bag indices: sidx[bag*30 + l], bag = p*2+side ----
#pragma unroll
    for (int i = 0; i < 4; ++i) {
        int e = t + i * 256;                    // 0..1023
        if (e < 480) {
            int p = e / 30, l = e - p * 30;
            sidx[p * 60 + l] = stm_idx[(pblk + p) * 30 + l];
        } else if (e < 960) {
            int e2 = e - 480;
            int p = e2 / 30, l = e2 - p * 30;
            sidx[p * 60 + 30 + l] = nstm_idx[(pblk + p) * 30 + l];
        }
    }
    __syncthreads();

    // ---- bag gather + sum + clip, 2 halves x 4 bags, 8 forced-in-flight ----
#pragma unroll 1
    for (int half = 0; half < 2; ++half) {
        const int  bagbase = w * 8 + half * 4;
        const int* ids     = sidx + bagbase * 30;

        float ac[4][8];
#pragma unroll
        for (int b = 0; b < 4; ++b)
#pragma unroll
            for (int j = 0; j < 8; ++j) ac[b][j] = 0.f;

        int id00 = ids[0 * 30], id01 = ids[0 * 30 + 1];
        int id10 = ids[1 * 30], id11 = ids[1 * 30 + 1];
        int id20 = ids[2 * 30], id21 = ids[2 * 30 + 1];
        int id30 = ids[3 * 30], id31 = ids[3 * 30 + 1];

#pragma unroll 1
        for (int lc = 0; lc < 30; lc += 2) {
            const unsigned int* p00 = embbf + (size_t)id00 * 256 + (lane << 2);
            const unsigned int* p01 = embbf + (size_t)id01 * 256 + (lane << 2);
            const unsigned int* p10 = embbf + (size_t)id10 * 256 + (lane << 2);
            const unsigned int* p11 = embbf + (size_t)id11 * 256 + (lane << 2);
            const unsigned int* p20 = embbf + (size_t)id20 * 256 + (lane << 2);
            const unsigned int* p21 = embbf + (size_t)id21 * 256 + (lane << 2);
            const unsigned int* p30 = embbf + (size_t)id30 * 256 + (lane << 2);
            const unsigned int* p31 = embbf + (size_t)id31 * 256 + (lane << 2);

            u32x4 v00, v01, v10, v11, v20, v21, v30, v31;
            asm volatile("global_load_dwordx4 %0, %1, off" : "=v"(v00) : "v"(p00));
            asm volatile("global_load_dwordx4 %0, %1, off" : "=v"(v01) : "v"(p01));
            asm volatile("global_load_dwordx4 %0, %1, off" : "=v"(v10) : "v"(p10));
            asm volatile("global_load_dwordx4 %0, %1, off" : "=v"(v11) : "v"(p11));
            asm volatile("global_load_dwordx4 %0, %1, off" : "=v"(v20) : "v"(p20));
            asm volatile("global_load_dwordx4 %0, %1, off" : "=v"(v21) : "v"(p21));
            asm volatile("global_load_dwordx4 %0, %1, off" : "=v"(v30) : "v"(p30));
            asm volatile("global_load_dwordx4 %0, %1, off" : "=v"(v31) : "v"(p31));

            // prefetch next round's indices under the vm wait (lgkm path)
            if (lc + 2 < 30) {
                id00 = ids[0 * 30 + lc + 2]; id01 = ids[0 * 30 + lc + 3];
                id10 = ids[1 * 30 + lc + 2]; id11 = ids[1 * 30 + lc + 3];
                id20 = ids[2 * 30 + lc + 2]; id21 = ids[2 * 30 + lc + 3];
                id30 = ids[3 * 30 + lc + 2]; id31 = ids[3 * 30 + lc + 3];
            }

            asm volatile("s_waitcnt vmcnt(0)" ::: "memory");
            __builtin_amdgcn_sched_barrier(0);

#define CONSUME(b, u)                                            \
            ac[b][0] += __uint_as_float(u[0] << 16);             \
            ac[b][1] += __uint_as_float(u[0] & 0xffff0000u);     \
            ac[b][2] += __uint_as_float(u[1] << 16);             \
            ac[b][3] += __uint_as_float(u[1] & 0xffff0000u);     \
            ac[b][4] += __uint_as_float(u[2] << 16);             \
            ac[b][5] += __uint_as_float(u[2] & 0xffff0000u);     \
            ac[b][6] += __uint_as_float(u[3] << 16);             \
            ac[b][7] += __uint_as_float(u[3] & 0xffff0000u);
            CONSUME(0, v00) CONSUME(0, v01)
            CONSUME(1, v10) CONSUME(1, v11)
            CONSUME(2, v20) CONSUME(2, v21)
            CONSUME(3, v30) CONSUME(3, v31)
#undef CONSUME
        }
        // write out the 4 bags (clip -> bf16 pack -> swizzled LDS store)
#pragma unroll
        for (int b = 0; b < 4; ++b) {
            const int bag  = bagbase + b;
            const int p    = bag >> 1;
            const int side = bag & 1;
            uint4 pk;
            pk.x = f2bf(clip01(ac[b][0])) | (f2bf(clip01(ac[b][1])) << 16);
            pk.y = f2bf(clip01(ac[b][2])) | (f2bf(clip01(ac[b][3])) << 16);
            pk.z = f2bf(clip01(ac[b][4])) | (f2bf(clip01(ac[b][5])) << 16);
            pk.w = f2bf(clip01(ac[b][6])) | (f2bf(clip01(ac[b][7])) << 16);
            const int col  = side * 1024 + lane * 16;
            const int addr = p * 2048 + (col ^ ((p & 7) << 4));
            *(uint4*)(xb + addr) = pk;
        }
    }
    __syncthreads();

    // ---- layer1 GEMM via MFMA (M=16, N=128, K=1024) ----
    const int l15 = lane & 15, lg = lane >> 4, lq = lane & 7;
    f32x4 acc0 = {}, acc1 = {};
    const int arow = l15 * 2048;
    const bf16x8* w1v = (const bf16x8*)w1f;
#pragma unroll 4
    for (int ks = 0; ks < 32; ++ks) {
        const int acol = (ks * 64 + lg * 16) ^ (lq << 4);
        bf16x8 a0  = *(const bf16x8*)(xb + arow + acol);
        bf16x8 bf0 = w1v[((2 * w + 0) * 32 + ks) * 64 + lane];
        bf16x8 bf1 = w1v[((2 * w + 1) * 32 + ks) * 64 + lane];
        acc0 = __builtin_amdgcn_mfma_f32_16x16x32_bf16(a0, bf0, acc0, 0, 0, 0);
        acc1 = __builtin_amdgcn_mfma_f32_16x16x32_bf16(a0, bf1, acc1, 0, 0, 0);
    }
    __syncthreads();   // x tile dead; smem becomes h1/w2/h2

    // ---- epilogue: bias + clip -> h1[16][132] ----
    {
        const int o0 = (2 * w + 0) * 16 + l15;
        const int o1 = (2 * w + 1) * 16 + l15;
        const float bb0 = b1[o0], bb1 = b1[o1];
#pragma unroll
        for (int r = 0; r < 4; ++r) {
            int p0 = lg * 4 + r;                // 0..15
            h1[p0 * 132 + o0] = clip01(acc0[r] + bb0);
            h1[p0 * 132 + o1] = clip01(acc1[r] + bb1);
        }
    }
    // stage W2 (32x128): 4096 floats, 16 per thread
#pragma unroll
    for (int i = 0; i < 16; ++i) {
        int f = t + i * 256;
        int o = f >> 7, k = f & 127;
        w2[o * 132 + k] = W2[o * 128 + k];
    }
    __syncthreads();

    // ---- layer2: 16 pos x 32 out; thread -> pos t>>4, 2 outputs ----
    {
        const int p2 = t >> 4;
        const int ob = (t & 15) * 2;
        float s0 = b2[ob], s1 = b2[ob + 1];
#pragma unroll
        for (int k4 = 0; k4 < 32; ++k4) {
            float4 h4 = *(const float4*)(h1 + p2 * 132 + k4 * 4);
            float4 wa = *(const float4*)(w2 + ob * 132 + k4 * 4);
            float4 wb = *(const float4*)(w2 + (ob + 1) * 132 + k4 * 4);
            s0 += h4.x * wa.x + h4.y * wa.y + h4.z * wa.z + h4.w * wa.w;
            s1 += h4.x * wb.x + h4.y * wb.y + h4.z * wb.z + h4.w * wb.w;
        }
        h2[p2 * 33 + ob]     = clip01(s0);
        h2[p2 * 33 + ob + 1] = clip01(s1);
    }
    __syncthreads();

    // ---- layer3 + tanh ----
    if (t < MT) {
        float s = b3[0];
#pragma unroll
        for (int k = 0; k < 32; ++k) s += h2[t * 33 + k] * W3[k];
        out[pblk + t] = tanhf(s);
    }
}

// ---------------------------------------------------------------------------
extern "C" void kernel_launch(void* const* d_in, const int* in_sizes, int n_in,
                              void* d_out, int out_size, void* d_ws, size_t ws_size,
                              hipStream_t stream) {
    const int*   stm_idx  = (const int*)  d_in[0];
    const int*   nstm_idx = (const int*)  d_in[2];
    const float* emb      = (const float*)d_in[4];
    const float* W1       = (const float*)d_in[5];
    const float* b1       = (const float*)d_in[6];
    const float* W2       = (const float*)d_in[7];
    const float* b2       = (const float*)d_in[8];
    const float* W3       = (const float*)d_in[9];
    const float* b3       = (const float*)d_in[10];
    float*       out      = (float*)d_out;

    unsigned int* embbf = (unsigned int*)d_ws;                       // 41,943,040 B
    unsigned int* w1f   = (unsigned int*)((char*)d_ws + 41943040);   // 262,144 B

    cvt_emb<<<2048, 256, 0, stream>>>(emb, embbf);
    prep_w1<<<64, 256, 0, stream>>>(W1, w1f);
    nnue_fused<<<NPOS / MT, 256, 0, stream>>>(stm_idx, nstm_idx, embbf, w1f,
                                              b1, W2, b2, W3, b3, out);
}

// Round 9
// 149.795 us; speedup vs baseline: 1.0500x; 1.0500x over previous
//
#include <hip/hip_runtime.h>
#include <math.h>

#define NPOS  16384
#define LBAG  30
#define NFEAT 40960
#define HDIM  512          // per side
#define MT    16           // positions per block

typedef short bf16x8 __attribute__((ext_vector_type(8)));
typedef float f32x4  __attribute__((ext_vector_type(4)));

__device__ __forceinline__ unsigned int f2bf(float f) {
    unsigned int u = __float_as_uint(f);
    return (u + 0x7fffu + ((u >> 16) & 1u)) >> 16;
}
__device__ __forceinline__ float clip01(float v) { return fminf(fmaxf(v, 0.f), 1.f); }

// ---------------------------------------------------------------------------
// Prep 1: emb fp32 -> bf16 into TWO half-tables (cols 0-255 -> A, 256-511 -> B),
// each [NFEAT][256] bf16 = 21 MB. r5-r8 evidence: gather is L2-miss bound
// (448 MB fabric @3.3 TB/s, invariant to occupancy/ILP). Halving the
// instantaneous working set (21 MB/pass vs 4 MB/XCD L2) raises hit rate.
// ---------------------------------------------------------------------------
__global__ __launch_bounds__(256) void cvt_emb_split(const float* __restrict__ src,
                                                     unsigned int* __restrict__ embA,
                                                     unsigned int* __restrict__ embB) {
    const int nchunk = NFEAT * HDIM / 8;             // 2,621,440 chunks of 8 floats
    int c = blockIdx.x * 256 + threadIdx.x;
    const int stride = gridDim.x * 256;
    for (; c < nchunk; c += stride) {
        const int row = c >> 6;                      // 64 chunks per 512-float row
        const int k   = c & 63;
        const float4 f0 = ((const float4*)src)[(size_t)c * 2];
        const float4 f1 = ((const float4*)src)[(size_t)c * 2 + 1];
        uint4 o;
        o.x = f2bf(f0.x) | (f2bf(f0.y) << 16);
        o.y = f2bf(f0.z) | (f2bf(f0.w) << 16);
        o.z = f2bf(f1.x) | (f2bf(f1.y) << 16);
        o.w = f2bf(f1.z) | (f2bf(f1.w) << 16);
        unsigned int* dst = (k < 32) ? (embA + (size_t)row * 128 + k * 4)
                                     : (embB + (size_t)row * 128 + (k - 32) * 4);
        *(uint4*)dst = o;
    }
}

// ---------------------------------------------------------------------------
// Prep 2: W1 [128][1024] fp32 -> bf16 in MFMA B-fragment order.
//   B[k][j] = W1[j][k], j = nf*16 + (lane&15), k = ks*32 + (lane>>4)*8 + b
// ---------------------------------------------------------------------------
__global__ __launch_bounds__(256) void prep_w1(const float* __restrict__ W1,
                                               unsigned int* __restrict__ dst) {
    int c = blockIdx.x * 256 + threadIdx.x;
    if (c >= 8 * 32 * 64) return;
    int l  = c & 63;
    int ks = (c >> 6) & 31;
    int nf = c >> 11;
    int o  = nf * 16 + (l & 15);
    int kb = ks * 32 + (l >> 4) * 8;
    float4 f0 = *(const float4*)(W1 + (size_t)o * 1024 + kb);
    float4 f1 = *(const float4*)(W1 + (size_t)o * 1024 + kb + 4);
    uint4 v;
    v.x = f2bf(f0.x) | (f2bf(f0.y) << 16);
    v.y = f2bf(f0.z) | (f2bf(f0.w) << 16);
    v.z = f2bf(f1.x) | (f2bf(f1.y) << 16);
    v.w = f2bf(f1.z) | (f2bf(f1.w) << 16);
    ((uint4*)dst)[c] = v;
}

// ---------------------------------------------------------------------------
// Fused kernel, round 9: two-pass column-split gather.
// Pass P (P=0: embA/cols 0-255, P=1: embB/cols 256-511): wave w handles
// positions p = w*4+pi; ONE wave-load covers BOTH sides of p (lanes 0-31 =
// stm half-row, lanes 32-63 = nstm half-row; 2 x 512B segments, fully
// coalesced 1KB). Per-pair acc = 8 VGPR, so the compiler has room to
// pipeline the 30-row loop (unroll 6).
//
// LDS map (36608 B): [0,32768) x tile (phase1) / h1|w2|h2 (phase2);
//                    [32768,36608) sidx[32 bags][30].
// Swizzle: byte = row*2048 + (col ^ ((row&7)<<4)) on write and A-frag read
// (uniform bijection on byte addresses -> 8/16B chunk-size independent).
// MFMA 16x16x32_bf16: A row=lane&15, k=(lane>>4)*8+b; C/D col=lane&15,
// row=(lane>>4)*4+reg [m89]. Wave w covers nf = 2w, 2w+1.
// ---------------------------------------------------------------------------
__global__ __launch_bounds__(256, 4) void nnue_fused(
    const int* __restrict__ stm_idx, const int* __restrict__ nstm_idx,
    const unsigned int* __restrict__ embA,      // [NFEAT][256] bf16 (cols 0-255)
    const unsigned int* __restrict__ embB,      // [NFEAT][256] bf16 (cols 256-511)
    const unsigned int* __restrict__ w1f,       // frag-ordered bf16
    const float* __restrict__ b1,
    const float* __restrict__ W2, const float* __restrict__ b2,
    const float* __restrict__ W3, const float* __restrict__ b3,
    float* __restrict__ out)
{
    __shared__ __align__(16) char smem[36608];
    char* xb   = smem;
    int*  sidx = (int*)(smem + 32768);
    float* h1  = (float*)smem;                  // [16][132]
    float* w2  = (float*)smem + 16 * 132;       // [32][132]
    float* h2  = (float*)smem + 48 * 132;       // [16][33]

    const int t    = threadIdx.x;               // 0..255
    const int pblk = blockIdx.x * MT;
    const int w    = t >> 6;                    // wave 0..3
    const int lane = t & 63;

    // ---- stage bag indices: sidx[bag*30 + l], bag = p*2+side ----
#pragma unroll
    for (int i = 0; i < 4; ++i) {
        int e = t + i * 256;                    // 0..1023
        if (e < 480) {
            int p = e / 30, l = e - p * 30;
            sidx[p * 60 + l] = stm_idx[(pblk + p) * 30 + l];
        } else if (e < 960) {
            int e2 = e - 480;
            int p = e2 / 30, l = e2 - p * 30;
            sidx[p * 60 + 30 + l] = nstm_idx[(pblk + p) * 30 + l];
        }
    }
    __syncthreads();

    // ---- two-pass gather: half the table working set per pass ----
    const int lhalf = lane >> 5;                // lane's side
    const int l31   = lane & 31;                // 16B chunk within 512B half-row
#pragma unroll 1
    for (int pass = 0; pass < 2; ++pass) {
        const unsigned int* __restrict__ tab = pass ? embB : embA;
        const int passbyte = pass << 9;         // 0 or 512
#pragma unroll 1
        for (int pi = 0; pi < 4; ++pi) {
            const int p    = w * 4 + pi;        // x row 0..15 (wave-uniform)
            const int* ids = sidx + (p * 2 + lhalf) * 30;   // per-lane-half bag
            float ac[8];
#pragma unroll
            for (int j = 0; j < 8; ++j) ac[j] = 0.f;
#pragma unroll 6
            for (int r = 0; r < 30; ++r) {
                const int id = ids[r];          // LDS read, 2-way broadcast
                const uint4 v = *(const uint4*)(tab + (size_t)id * 128 + (l31 << 2));
                ac[0] += __uint_as_float(v.x << 16);
                ac[1] += __uint_as_float(v.x & 0xffff0000u);
                ac[2] += __uint_as_float(v.y << 16);
                ac[3] += __uint_as_float(v.y & 0xffff0000u);
                ac[4] += __uint_as_float(v.z << 16);
                ac[5] += __uint_as_float(v.z & 0xffff0000u);
                ac[6] += __uint_as_float(v.w << 16);
                ac[7] += __uint_as_float(v.w & 0xffff0000u);
            }
            uint4 pk;
            pk.x = f2bf(clip01(ac[0])) | (f2bf(clip01(ac[1])) << 16);
            pk.y = f2bf(clip01(ac[2])) | (f2bf(clip01(ac[3])) << 16);
            pk.z = f2bf(clip01(ac[4])) | (f2bf(clip01(ac[5])) << 16);
            pk.w = f2bf(clip01(ac[6])) | (f2bf(clip01(ac[7])) << 16);
            const int colb = (lhalf << 10) + passbyte + (l31 << 4);
            const int addr = p * 2048 + (colb ^ ((p & 7) << 4));
            *(uint4*)(xb + addr) = pk;
        }
    }
    __syncthreads();

    // ---- layer1 GEMM via MFMA (M=16, N=128, K=1024) ----
    const int l15 = lane & 15, lg = lane >> 4, lq = lane & 7;
    f32x4 acc0 = {}, acc1 = {};
    const int arow = l15 * 2048;
    const bf16x8* w1v = (const bf16x8*)w1f;
#pragma unroll 4
    for (int ks = 0; ks < 32; ++ks) {
        const int acol = (ks * 64 + lg * 16) ^ (lq << 4);
        bf16x8 a0  = *(const bf16x8*)(xb + arow + acol);
        bf16x8 bf0 = w1v[((2 * w + 0) * 32 + ks) * 64 + lane];
        bf16x8 bf1 = w1v[((2 * w + 1) * 32 + ks) * 64 + lane];
        acc0 = __builtin_amdgcn_mfma_f32_16x16x32_bf16(a0, bf0, acc0, 0, 0, 0);
        acc1 = __builtin_amdgcn_mfma_f32_16x16x32_bf16(a0, bf1, acc1, 0, 0, 0);
    }
    __syncthreads();   // x tile dead; smem becomes h1/w2/h2

    // ---- epilogue: bias + clip -> h1[16][132] ----
    {
        const int o0 = (2 * w + 0) * 16 + l15;
        const int o1 = (2 * w + 1) * 16 + l15;
        const float bb0 = b1[o0], bb1 = b1[o1];
#pragma unroll
        for (int r = 0; r < 4; ++r) {
            int p0 = lg * 4 + r;                // 0..15
            h1[p0 * 132 + o0] = clip01(acc0[r] + bb0);
            h1[p0 * 132 + o1] = clip01(acc1[r] + bb1);
        }
    }
    // stage W2 (32x128): 4096 floats, 16 per thread
#pragma unroll
    for (int i = 0; i < 16; ++i) {
        int f = t + i * 256;
        int o = f >> 7, k = f & 127;
        w2[o * 132 + k] = W2[o * 128 + k];
    }
    __syncthreads();

    // ---- layer2: 16 pos x 32 out; thread -> pos t>>4, 2 outputs ----
    {
        const int p2 = t >> 4;
        const int ob = (t & 15) * 2;
        float s0 = b2[ob], s1 = b2[ob + 1];
#pragma unroll
        for (int k4 = 0; k4 < 32; ++k4) {
            float4 h4 = *(const float4*)(h1 + p2 * 132 + k4 * 4);
            float4 wa = *(const float4*)(w2 + ob * 132 + k4 * 4);
            float4 wb = *(const float4*)(w2 + (ob + 1) * 132 + k4 * 4);
            s0 += h4.x * wa.x + h4.y * wa.y + h4.z * wa.z + h4.w * wa.w;
            s1 += h4.x * wb.x + h4.y * wb.y + h4.z * wb.z + h4.w * wb.w;
        }
        h2[p2 * 33 + ob]     = clip01(s0);
        h2[p2 * 33 + ob + 1] = clip01(s1);
    }
    __syncthreads();

    // ---- layer3 + tanh ----
    if (t < MT) {
        float s = b3[0];
#pragma unroll
        for (int k = 0; k < 32; ++k) s += h2[t * 33 + k] * W3[k];
        out[pblk + t] = tanhf(s);
    }
}

// ---------------------------------------------------------------------------
extern "C" void kernel_launch(void* const* d_in, const int* in_sizes, int n_in,
                              void* d_out, int out_size, void* d_ws, size_t ws_size,
                              hipStream_t stream) {
    const int*   stm_idx  = (const int*)  d_in[0];
    const int*   nstm_idx = (const int*)  d_in[2];
    const float* emb      = (const float*)d_in[4];
    const float* W1       = (const float*)d_in[5];
    const float* b1       = (const float*)d_in[6];
    const float* W2       = (const float*)d_in[7];
    const float* b2       = (const float*)d_in[8];
    const float* W3       = (const float*)d_in[9];
    const float* b3       = (const float*)d_in[10];
    float*       out      = (float*)d_out;

    unsigned int* embA = (unsigned int*)d_ws;                        // 20,971,520 B
    unsigned int* embB = (unsigned int*)((char*)d_ws + 20971520);    // 20,971,520 B
    unsigned int* w1f  = (unsigned int*)((char*)d_ws + 41943040);    // 262,144 B

    cvt_emb_split<<<2048, 256, 0, stream>>>(emb, embA, embB);
    prep_w1<<<64, 256, 0, stream>>>(W1, w1f);
    nnue_fused<<<NPOS / MT, 256, 0, stream>>>(stm_idx, nstm_idx, embA, embB, w1f,
                                              b1, W2, b2, W3, b3, out);
}

// Round 10
// 119.167 us; speedup vs baseline: 1.3198x; 1.2570x over previous
//
#include <hip/hip_runtime.h>
#include <math.h>

#define NPOS  16384
#define LBAG  30
#define NFEAT 40960
#define HDIM  512          // per side
#define MT    16           // positions per block (mlp2)

typedef short bf16x8 __attribute__((ext_vector_type(8)));
typedef float f32x4  __attribute__((ext_vector_type(4)));

__device__ __forceinline__ unsigned int f2bf(float f) {
    unsigned int u = __float_as_uint(f);
    return (u + 0x7fffu + ((u >> 16) & 1u)) >> 16;
}
__device__ __forceinline__ float clip01(float v) { return fminf(fmaxf(v, 0.f), 1.f); }

// ---------------------------------------------------------------------------
// Prep 1: emb fp32 -> bf16 single table [NFEAT][512] (uint pairs). ~21us.
// ---------------------------------------------------------------------------
__global__ __launch_bounds__(256) void cvt_emb(const float* __restrict__ src,
                                               unsigned int* __restrict__ dst) {
    const int nchunk = NFEAT * HDIM / 8;
    int c = blockIdx.x * 256 + threadIdx.x;
    const int stride = gridDim.x * 256;
    for (; c < nchunk; c += stride) {
        float4 f0 = ((const float4*)src)[(size_t)c * 2];
        float4 f1 = ((const float4*)src)[(size_t)c * 2 + 1];
        uint4 o;
        o.x = f2bf(f0.x) | (f2bf(f0.y) << 16);
        o.y = f2bf(f0.z) | (f2bf(f0.w) << 16);
        o.z = f2bf(f1.x) | (f2bf(f1.y) << 16);
        o.w = f2bf(f1.z) | (f2bf(f1.w) << 16);
        ((uint4*)dst)[c] = o;
    }
}

// ---------------------------------------------------------------------------
// Prep 2: W1 [128][1024] fp32 -> bf16 in MFMA B-fragment order.
//   B[k][j] = W1[j][k], j = nf*16 + (lane&15), k = ks*32 + (lane>>4)*8 + b
// ---------------------------------------------------------------------------
__global__ __launch_bounds__(256) void prep_w1(const float* __restrict__ W1,
                                               unsigned int* __restrict__ dst) {
    int c = blockIdx.x * 256 + threadIdx.x;
    if (c >= 8 * 32 * 64) return;
    int l  = c & 63;
    int ks = (c >> 6) & 31;
    int nf = c >> 11;
    int o  = nf * 16 + (l & 15);
    int kb = ks * 32 + (l >> 4) * 8;
    float4 f0 = *(const float4*)(W1 + (size_t)o * 1024 + kb);
    float4 f1 = *(const float4*)(W1 + (size_t)o * 1024 + kb + 4);
    uint4 v;
    v.x = f2bf(f0.x) | (f2bf(f0.y) << 16);
    v.y = f2bf(f0.z) | (f2bf(f0.w) << 16);
    v.z = f2bf(f1.x) | (f2bf(f1.y) << 16);
    v.w = f2bf(f1.z) | (f2bf(f1.w) << 16);
    ((uint4*)dst)[c] = v;
}

// ---------------------------------------------------------------------------
// Kernel 1, round 10: XCD-sliced gather. r5-r9 evidence: gather is bound by
// L2-miss fabric traffic, whose floor is 8 XCDs x 42 MB = 336 MB when every
// XCD touches the whole table (observed 412-448 MB; occupancy/ILP null).
// Fix: block b handles column-slice (b&7) = 64 table cols = 128 B/row = one
// cache line. Under round-robin blockIdx->XCD dispatch, slice s stays on
// XCD s: per-XCD working set 5.25 MB -> table fabric traffic ~42 MB total.
// Mapping wrong => only slower, never incorrect.
//
// 2048 blocks x 256 thr (8/CU, 32 waves/CU). Each 8-lane group owns one bag:
// 30 x 128B line-gathers, fp32 acc[8], clip -> bf16 -> x written DIRECTLY in
// the swizzled layout mlp2 stages: byte = p*2048 + (colb ^ ((p&7)<<4)),
// colb = side*1024 + slice*128 + li*16. XOR permutes 16B chunks inside the
// 128B line, so group writes stay line-contiguous.
// ---------------------------------------------------------------------------
__global__ __launch_bounds__(256) void gather_slices(
    const int* __restrict__ stm_idx, const int* __restrict__ nstm_idx,
    const unsigned int* __restrict__ embbf,     // [NFEAT][256] uints (512 bf16)
    unsigned int* __restrict__ xg)              // [NPOS][512] uints, swizzled
{
    __shared__ int sidx[3840];                  // 64 pos x 2 sides x 30
    const int t     = threadIdx.x;
    const int slice = blockIdx.x & 7;
    const int pblk  = (blockIdx.x >> 3) * 64;

    // stage indices, bag-major: sidx[(p*2+side)*30 + r]
#pragma unroll
    for (int i = 0; i < 15; ++i) {
        int e = t + i * 256;                    // 0..3839
        if (e < 1920) {
            int p = e / 30, r = e - p * 30;
            sidx[p * 60 + r] = stm_idx[(pblk + p) * 30 + r];
        } else {
            int e2 = e - 1920;
            int p = e2 / 30, r = e2 - p * 30;
            sidx[p * 60 + 30 + r] = nstm_idx[(pblk + p) * 30 + r];
        }
    }
    __syncthreads();

    const int lane = t & 63, w = t >> 6;
    const int g  = lane >> 3;                   // lane-group 0..7 (one bag)
    const int li = lane & 7;                    // 16B chunk within 128B line
    const unsigned int tabofs = slice * 32 + li * 4;

#pragma unroll 1
    for (int it = 0; it < 4; ++it) {
        const int bag  = it * 32 + w * 8 + g;   // 0..127
        const int p    = bag >> 1;
        const int side = bag & 1;
        const int* ids = sidx + bag * 30;       // banks 30g%32: all distinct
        float ac[8];
#pragma unroll
        for (int j = 0; j < 8; ++j) ac[j] = 0.f;
#pragma unroll 6
        for (int r = 0; r < 30; ++r) {
            const int id = ids[r];
            const uint4 v = *(const uint4*)(embbf + (size_t)id * 256 + tabofs);
            ac[0] += __uint_as_float(v.x << 16);
            ac[1] += __uint_as_float(v.x & 0xffff0000u);
            ac[2] += __uint_as_float(v.y << 16);
            ac[3] += __uint_as_float(v.y & 0xffff0000u);
            ac[4] += __uint_as_float(v.z << 16);
            ac[5] += __uint_as_float(v.z & 0xffff0000u);
            ac[6] += __uint_as_float(v.w << 16);
            ac[7] += __uint_as_float(v.w & 0xffff0000u);
        }
        uint4 pk;
        pk.x = f2bf(clip01(ac[0])) | (f2bf(clip01(ac[1])) << 16);
        pk.y = f2bf(clip01(ac[2])) | (f2bf(clip01(ac[3])) << 16);
        pk.z = f2bf(clip01(ac[4])) | (f2bf(clip01(ac[5])) << 16);
        pk.w = f2bf(clip01(ac[6])) | (f2bf(clip01(ac[7])) << 16);
        const int colb = (side * 1024 + slice * 128 + li * 16) ^ ((p & 7) << 4);
        *(uint4*)((char*)xg + (size_t)(pblk + p) * 2048 + colb) = pk;
    }
}

// ---------------------------------------------------------------------------
// Kernel 2: MLP. x is already in the swizzled LDS layout -> the 32KB stage is
// a LINEAR copy (global byte == LDS byte for the block's 16 rows, since
// (p%16)&7 == p&7). MFMA phase and layers 2/3 identical to r9's (verified).
// LDS: 32768 B phase1 x-tile; phase2 h1[16][132]|w2[32][132]|h2[16][33]=27456.
// ---------------------------------------------------------------------------
__global__ __launch_bounds__(256, 4) void mlp2(
    const unsigned int* __restrict__ xg,        // [NPOS][512] uints, swizzled
    const unsigned int* __restrict__ w1f,       // frag-ordered bf16
    const float* __restrict__ b1,
    const float* __restrict__ W2, const float* __restrict__ b2,
    const float* __restrict__ W3, const float* __restrict__ b3,
    float* __restrict__ out)
{
    __shared__ __align__(16) char smem[32768];
    char* xb   = smem;
    float* h1  = (float*)smem;                  // [16][132]
    float* w2  = (float*)smem + 16 * 132;       // [32][132]
    float* h2  = (float*)smem + 48 * 132;       // [16][33]

    const int t    = threadIdx.x;               // 0..255
    const int pblk = blockIdx.x * MT;
    const int w    = t >> 6;
    const int lane = t & 63;

    // ---- stage x tile: linear 32KB copy (coalesced 16B/lane) ----
    {
        const uint4* src = (const uint4*)((const char*)xg + (size_t)pblk * 2048);
#pragma unroll
        for (int i = 0; i < 8; ++i) {
            int f = t + i * 256;                // 0..2047 uint4 chunks
            *(uint4*)(xb + f * 16) = src[f];
        }
    }
    __syncthreads();

    // ---- layer1 GEMM via MFMA (M=16, N=128, K=1024) ----
    const int l15 = lane & 15, lg = lane >> 4, lq = lane & 7;
    f32x4 acc0 = {}, acc1 = {};
    const int arow = l15 * 2048;
    const bf16x8* w1v = (const bf16x8*)w1f;
#pragma unroll 4
    for (int ks = 0; ks < 32; ++ks) {
        const int acol = (ks * 64 + lg * 16) ^ (lq << 4);
        bf16x8 a0  = *(const bf16x8*)(xb + arow + acol);
        bf16x8 bf0 = w1v[((2 * w + 0) * 32 + ks) * 64 + lane];
        bf16x8 bf1 = w1v[((2 * w + 1) * 32 + ks) * 64 + lane];
        acc0 = __builtin_amdgcn_mfma_f32_16x16x32_bf16(a0, bf0, acc0, 0, 0, 0);
        acc1 = __builtin_amdgcn_mfma_f32_16x16x32_bf16(a0, bf1, acc1, 0, 0, 0);
    }
    __syncthreads();   // x tile dead; smem becomes h1/w2/h2

    // ---- epilogue: bias + clip -> h1[16][132] ----
    {
        const int o0 = (2 * w + 0) * 16 + l15;
        const int o1 = (2 * w + 1) * 16 + l15;
        const float bb0 = b1[o0], bb1 = b1[o1];
#pragma unroll
        for (int r = 0; r < 4; ++r) {
            int p0 = lg * 4 + r;
            h1[p0 * 132 + o0] = clip01(acc0[r] + bb0);
            h1[p0 * 132 + o1] = clip01(acc1[r] + bb1);
        }
    }
    // stage W2 (32x128)
#pragma unroll
    for (int i = 0; i < 16; ++i) {
        int f = t + i * 256;
        int o = f >> 7, k = f & 127;
        w2[o * 132 + k] = W2[o * 128 + k];
    }
    __syncthreads();

    // ---- layer2: 16 pos x 32 out ----
    {
        const int p2 = t >> 4;
        const int ob = (t & 15) * 2;
        float s0 = b2[ob], s1 = b2[ob + 1];
#pragma unroll
        for (int k4 = 0; k4 < 32; ++k4) {
            float4 h4 = *(const float4*)(h1 + p2 * 132 + k4 * 4);
            float4 wa = *(const float4*)(w2 + ob * 132 + k4 * 4);
            float4 wb = *(const float4*)(w2 + (ob + 1) * 132 + k4 * 4);
            s0 += h4.x * wa.x + h4.y * wa.y + h4.z * wa.z + h4.w * wa.w;
            s1 += h4.x * wb.x + h4.y * wb.y + h4.z * wb.z + h4.w * wb.w;
        }
        h2[p2 * 33 + ob]     = clip01(s0);
        h2[p2 * 33 + ob + 1] = clip01(s1);
    }
    __syncthreads();

    // ---- layer3 + tanh ----
    if (t < MT) {
        float s = b3[0];
#pragma unroll
        for (int k = 0; k < 32; ++k) s += h2[t * 33 + k] * W3[k];
        out[pblk + t] = tanhf(s);
    }
}

// ---------------------------------------------------------------------------
extern "C" void kernel_launch(void* const* d_in, const int* in_sizes, int n_in,
                              void* d_out, int out_size, void* d_ws, size_t ws_size,
                              hipStream_t stream) {
    const int*   stm_idx  = (const int*)  d_in[0];
    const int*   nstm_idx = (const int*)  d_in[2];
    const float* emb      = (const float*)d_in[4];
    const float* W1       = (const float*)d_in[5];
    const float* b1       = (const float*)d_in[6];
    const float* W2       = (const float*)d_in[7];
    const float* b2       = (const float*)d_in[8];
    const float* W3       = (const float*)d_in[9];
    const float* b3       = (const float*)d_in[10];
    float*       out      = (float*)d_out;

    unsigned int* embbf = (unsigned int*)d_ws;                        // 41,943,040 B
    unsigned int* w1f   = (unsigned int*)((char*)d_ws + 41943040);    //    262,144 B
    unsigned int* xg    = (unsigned int*)((char*)d_ws + 42205184);    // 33,554,432 B

    cvt_emb<<<2048, 256, 0, stream>>>(emb, embbf);
    prep_w1<<<64, 256, 0, stream>>>(W1, w1f);
    gather_slices<<<2048, 256, 0, stream>>>(stm_idx, nstm_idx, embbf, xg);
    mlp2<<<NPOS / MT, 256, 0, stream>>>(xg, w1f, b1, W2, b2, W3, b3, out);
}